// Round 1
// baseline (488.448 us; speedup 1.0000x reference)
//
#include <hip/hip_runtime.h>
#include <hip/hip_bf16.h>

#define NE 768
#define NH 12
#define HD 64
#define BB 4
#define TT 2048
#define ROWS (BB*TT)  // 8192

typedef __attribute__((ext_vector_type(8))) short bf16x8;
typedef __attribute__((ext_vector_type(4))) float f32x4;

__device__ __forceinline__ short f2bf(float f) {
  __hip_bfloat16 h = __float2bfloat16(f);
  union { __hip_bfloat16 h; short s; } u; u.h = h; return u.s;
}

__device__ __forceinline__ void gload16(const void* g, void* l) {
  __builtin_amdgcn_global_load_lds(
      (const __attribute__((address_space(1))) void*)g,
      (__attribute__((address_space(3))) void*)l,
      16, 0, 0);
}

// ---------------- weight convert + transpose: W[K][N] f32 -> Wt[N][K] bf16 ----
__global__ __launch_bounds__(256) void wtrans_kernel(
    const float* __restrict__ W, short* __restrict__ Wt, int K, int N) {
  __shared__ short tile[64 * 65];
  int k0 = blockIdx.x * 64, n0 = blockIdx.y * 64;
  int t = threadIdx.x;
#pragma unroll
  for (int p = 0; p < 16; ++p) {
    int idx = p * 256 + t;
    int r = idx >> 6, c = idx & 63;
    tile[r * 65 + c] = f2bf(W[(size_t)(k0 + r) * N + n0 + c]);
  }
  __syncthreads();
#pragma unroll
  for (int p = 0; p < 16; ++p) {
    int idx = p * 256 + t;
    int rr = idx >> 6, cc = idx & 63;
    Wt[(size_t)(n0 + rr) * K + k0 + cc] = tile[cc * 65 + rr];
  }
}

// ---------------- LayerNorm: fp32 in -> bf16 out, one wave per row ----------
__global__ __launch_bounds__(64) void ln_kernel(
    const float* __restrict__ x, const float* __restrict__ g,
    const float* __restrict__ b, short* __restrict__ out) {
  int row = blockIdx.x, l = threadIdx.x;
  const float* xr = x + (size_t)row * NE;
  float4 v[3];
  float s = 0.f, ss = 0.f;
#pragma unroll
  for (int i = 0; i < 3; ++i) {
    v[i] = *reinterpret_cast<const float4*>(xr + l * 4 + i * 256);
    s += v[i].x + v[i].y + v[i].z + v[i].w;
    ss += v[i].x * v[i].x + v[i].y * v[i].y + v[i].z * v[i].z + v[i].w * v[i].w;
  }
#pragma unroll
  for (int m = 1; m < 64; m <<= 1) {
    s += __shfl_xor(s, m);
    ss += __shfl_xor(ss, m);
  }
  float mu = s * (1.0f / NE);
  float var = ss * (1.0f / NE) - mu * mu;
  float rstd = rsqrtf(var + 1e-5f);
#pragma unroll
  for (int i = 0; i < 3; ++i) {
    float4 gv = *reinterpret_cast<const float4*>(g + l * 4 + i * 256);
    float4 bv = *reinterpret_cast<const float4*>(b + l * 4 + i * 256);
    short4 o;
    o.x = f2bf((v[i].x - mu) * rstd * gv.x + bv.x);
    o.y = f2bf((v[i].y - mu) * rstd * gv.y + bv.y);
    o.z = f2bf((v[i].z - mu) * rstd * gv.z + bv.z);
    o.w = f2bf((v[i].w - mu) * rstd * gv.w + bv.w);
    *reinterpret_cast<short4*>(out + (size_t)row * NE + l * 4 + i * 256) = o;
  }
}

// ---------------- GEMM: C[M][N] = A[M][K](bf16) * Bt[N][K](bf16)^T + epi ----
// EPI 0: out bf16 = acc + bias
// EPI 1: out bf16 = gelu_exact(acc + bias)
// EPI 2: out f32  = acc + bias + resid
template <int EPI>
__global__ __launch_bounds__(256) void gemm_kernel(
    const short* __restrict__ A, const short* __restrict__ Bt,
    const float* __restrict__ bias, const float* __restrict__ resid,
    void* __restrict__ Cout, int M, int N, int K) {
  __shared__ short As[128 * 32];
  __shared__ short Bs[128 * 32];
  int t = threadIdx.x;
  int w = t >> 6, l = t & 63;
  int wr = w >> 1, wc = w & 1;
  int bn = blockIdx.x, bm = blockIdx.y;
  int lr = l & 15, lkb = (l >> 4) * 8;

  f32x4 acc[4][4];
#pragma unroll
  for (int i = 0; i < 4; ++i)
#pragma unroll
    for (int j = 0; j < 4; ++j) acc[i][j] = (f32x4){0.f, 0.f, 0.f, 0.f};

  const short* ga = A + (size_t)(bm * 128 + (t >> 2)) * K + (t & 3) * 8;
  const short* gb = Bt + (size_t)(bn * 128 + (t >> 2)) * K + (t & 3) * 8;
  short* lA = As + t * 8;
  short* lB = Bs + t * 8;
  int nk = K >> 5;
  for (int kt = 0; kt < nk; ++kt) {
    __syncthreads();
    gload16(ga, lA);
    gload16(ga + (size_t)64 * K, lA + 64 * 32);
    gload16(gb, lB);
    gload16(gb + (size_t)64 * K, lB + 64 * 32);
    ga += 32; gb += 32;
    __syncthreads();
    bf16x8 af[4], bfr[4];
#pragma unroll
    for (int i = 0; i < 4; ++i)
      af[i] = *reinterpret_cast<const bf16x8*>(As + (wr * 64 + i * 16 + lr) * 32 + lkb);
#pragma unroll
    for (int j = 0; j < 4; ++j)
      bfr[j] = *reinterpret_cast<const bf16x8*>(Bs + (wc * 64 + j * 16 + lr) * 32 + lkb);
#pragma unroll
    for (int i = 0; i < 4; ++i)
#pragma unroll
      for (int j = 0; j < 4; ++j)
        acc[i][j] = __builtin_amdgcn_mfma_f32_16x16x32_bf16(af[i], bfr[j], acc[i][j], 0, 0, 0);
  }

  int rbase = bm * 128 + wr * 64;
  int cbase = bn * 128 + wc * 64;
#pragma unroll
  for (int i = 0; i < 4; ++i) {
#pragma unroll
    for (int r = 0; r < 4; ++r) {
      int row = rbase + i * 16 + (l >> 4) * 4 + r;
#pragma unroll
      for (int j = 0; j < 4; ++j) {
        int col = cbase + j * 16 + lr;
        float v = acc[i][j][r] + bias[col];
        if (EPI == 0) {
          ((short*)Cout)[(size_t)row * N + col] = f2bf(v);
        } else if (EPI == 1) {
          v = 0.5f * v * (1.0f + erff(v * 0.70710678118654752f));
          ((short*)Cout)[(size_t)row * N + col] = f2bf(v);
        } else {
          ((float*)Cout)[(size_t)row * N + col] = v + resid[(size_t)row * N + col];
        }
      }
    }
  }
}

// ---------------- causal flash attention over qkv buffer ---------------------
// qkv: [ROWS][3*NE] bf16 (q|k|v). y: [ROWS][NE] bf16.
__global__ __launch_bounds__(256) void attn_kernel(
    const short* __restrict__ qkv, short* __restrict__ y) {
  __shared__ short Ks[64 * 72];
  __shared__ short Vt[64 * 72];  // Vt[hd][kpos]
  __shared__ short Ps[4 * 16 * 72];
  int t = threadIdx.x, w = t >> 6, l = t & 63;
  int lr = l & 15, lkb = (l >> 4) * 8;
  int qt = blockIdx.x;
  int bh = blockIdx.y;
  int b = bh / NH, h = bh % NH;
  int qbase = qt * 64;

  const short* qrow = qkv + (size_t)(b * TT + qbase + w * 16 + lr) * (3 * NE) + h * HD + lkb;
  bf16x8 qf0 = *reinterpret_cast<const bf16x8*>(qrow);
  bf16x8 qf1 = *reinterpret_cast<const bf16x8*>(qrow + 32);

  f32x4 o[4];
#pragma unroll
  for (int j = 0; j < 4; ++j) o[j] = (f32x4){0.f, 0.f, 0.f, 0.f};
  float m_run[4], l_run[4];
#pragma unroll
  for (int r = 0; r < 4; ++r) { m_run[r] = -3e38f; l_run[r] = 0.f; }

  short* Psw = Ps + w * 16 * 72;
  int nkv = qt + 1;
  for (int kt = 0; kt < nkv; ++kt) {
    int kvbase = kt * 64;
    __syncthreads();
#pragma unroll
    for (int i = 0; i < 2; ++i) {
      int idx = t + i * 256;
      int r = idx >> 3, c = (idx & 7) * 8;
      const short* kg = qkv + (size_t)(b * TT + kvbase + r) * (3 * NE) + NE + h * HD + c;
      *reinterpret_cast<bf16x8*>(&Ks[r * 72 + c]) = *reinterpret_cast<const bf16x8*>(kg);
      const short* vg = qkv + (size_t)(b * TT + kvbase + r) * (3 * NE) + 2 * NE + h * HD + c;
      bf16x8 vv = *reinterpret_cast<const bf16x8*>(vg);
#pragma unroll
      for (int j = 0; j < 8; ++j) Vt[(c + j) * 72 + r] = vv[j];
    }
    __syncthreads();

    f32x4 s[4];
#pragma unroll
    for (int nt = 0; nt < 4; ++nt) {
      bf16x8 kf0 = *reinterpret_cast<const bf16x8*>(&Ks[(nt * 16 + lr) * 72 + lkb]);
      bf16x8 kf1 = *reinterpret_cast<const bf16x8*>(&Ks[(nt * 16 + lr) * 72 + lkb + 32]);
      f32x4 st = (f32x4){0.f, 0.f, 0.f, 0.f};
      st = __builtin_amdgcn_mfma_f32_16x16x32_bf16(qf0, kf0, st, 0, 0, 0);
      st = __builtin_amdgcn_mfma_f32_16x16x32_bf16(qf1, kf1, st, 0, 0, 0);
      s[nt] = st;
    }
    int q0 = qbase + w * 16 + (l >> 4) * 4;
#pragma unroll
    for (int nt = 0; nt < 4; ++nt) {
      int kcol = kvbase + nt * 16 + lr;
#pragma unroll
      for (int r = 0; r < 4; ++r) {
        float v = s[nt][r] * 0.125f;
        s[nt][r] = (kcol <= q0 + r) ? v : -3e38f;
      }
    }
#pragma unroll
    for (int r = 0; r < 4; ++r) {
      float mb = fmaxf(fmaxf(s[0][r], s[1][r]), fmaxf(s[2][r], s[3][r]));
      mb = fmaxf(mb, __shfl_xor(mb, 1));
      mb = fmaxf(mb, __shfl_xor(mb, 2));
      mb = fmaxf(mb, __shfl_xor(mb, 4));
      mb = fmaxf(mb, __shfl_xor(mb, 8));
      float mn = fmaxf(m_run[r], mb);
      float al = __expf(m_run[r] - mn);
      m_run[r] = mn;
      float rs = 0.f;
#pragma unroll
      for (int nt = 0; nt < 4; ++nt) {
        float p = __expf(s[nt][r] - mn);
        s[nt][r] = p;
        rs += p;
      }
      rs += __shfl_xor(rs, 1);
      rs += __shfl_xor(rs, 2);
      rs += __shfl_xor(rs, 4);
      rs += __shfl_xor(rs, 8);
      l_run[r] = l_run[r] * al + rs;
#pragma unroll
      for (int j = 0; j < 4; ++j) o[j][r] *= al;
    }
    // P -> LDS (wave-private), bf16
#pragma unroll
    for (int nt = 0; nt < 4; ++nt)
#pragma unroll
      for (int r = 0; r < 4; ++r)
        Psw[((l >> 4) * 4 + r) * 72 + nt * 16 + lr] = f2bf(s[nt][r]);
    // PV
#pragma unroll
    for (int j = 0; j < 4; ++j) {
#pragma unroll
      for (int ks = 0; ks < 2; ++ks) {
        bf16x8 pf = *reinterpret_cast<const bf16x8*>(&Psw[lr * 72 + ks * 32 + lkb]);
        bf16x8 vf = *reinterpret_cast<const bf16x8*>(&Vt[(j * 16 + lr) * 72 + ks * 32 + lkb]);
        o[j] = __builtin_amdgcn_mfma_f32_16x16x32_bf16(pf, vf, o[j], 0, 0, 0);
      }
    }
  }
#pragma unroll
  for (int r = 0; r < 4; ++r) {
    float inv = 1.0f / l_run[r];
    size_t row = (size_t)(b * TT + qbase + w * 16 + (l >> 4) * 4 + r);
#pragma unroll
    for (int j = 0; j < 4; ++j)
      y[row * NE + h * HD + j * 16 + lr] = f2bf(o[j][r] * inv);
  }
}

extern "C" void kernel_launch(void* const* d_in, const int* in_sizes, int n_in,
                              void* d_out, int out_size, void* d_ws, size_t ws_size,
                              hipStream_t stream) {
  (void)in_sizes; (void)n_in; (void)out_size; (void)ws_size;
  const float* x       = (const float*)d_in[0];
  const float* ln1_g   = (const float*)d_in[1];
  const float* ln1_b   = (const float*)d_in[2];
  const float* w_attn  = (const float*)d_in[3];
  const float* b_attn  = (const float*)d_in[4];
  const float* w_aproj = (const float*)d_in[5];
  const float* b_aproj = (const float*)d_in[6];
  const float* ln2_g   = (const float*)d_in[7];
  const float* ln2_b   = (const float*)d_in[8];
  const float* w_fc    = (const float*)d_in[9];
  const float* b_fc    = (const float*)d_in[10];
  const float* w_mproj = (const float*)d_in[11];
  const float* b_mproj = (const float*)d_in[12];

  char* ws = (char*)d_ws;
  size_t off = 0;
  auto alloc = [&](size_t bytes) {
    char* p = ws + off;
    off += (bytes + 255) & ~(size_t)255;
    return p;
  };
  short* wt_attn  = (short*)alloc((size_t)2304 * 768 * 2);
  short* wt_aproj = (short*)alloc((size_t)768 * 768 * 2);
  short* wt_fc    = (short*)alloc((size_t)3072 * 768 * 2);
  short* wt_mproj = (short*)alloc((size_t)768 * 3072 * 2);
  short* lnb  = (short*)alloc((size_t)ROWS * 768 * 2);
  short* qkvb = (short*)alloc((size_t)ROWS * 3072 * 2);  // shared qkv (2304) / h (3072)
  short* yb   = (short*)alloc((size_t)ROWS * 768 * 2);
  float* x2   = (float*)alloc((size_t)ROWS * 768 * 4);

  // weights -> bf16, transposed to [N][K]
  wtrans_kernel<<<dim3(768 / 64, 2304 / 64), 256, 0, stream>>>(w_attn, wt_attn, 768, 2304);
  wtrans_kernel<<<dim3(768 / 64, 768 / 64), 256, 0, stream>>>(w_aproj, wt_aproj, 768, 768);
  wtrans_kernel<<<dim3(768 / 64, 3072 / 64), 256, 0, stream>>>(w_fc, wt_fc, 768, 3072);
  wtrans_kernel<<<dim3(3072 / 64, 768 / 64), 256, 0, stream>>>(w_mproj, wt_mproj, 3072, 768);

  // LN1
  ln_kernel<<<ROWS, 64, 0, stream>>>(x, ln1_g, ln1_b, lnb);
  // QKV = ln1(x) @ w_attn + b_attn
  gemm_kernel<0><<<dim3(2304 / 128, ROWS / 128), 256, 0, stream>>>(
      lnb, wt_attn, b_attn, nullptr, qkvb, ROWS, 2304, 768);
  // attention
  attn_kernel<<<dim3(TT / 64, BB * NH), 256, 0, stream>>>(qkvb, yb);
  // x2 = x + y @ w_aproj + b_aproj
  gemm_kernel<2><<<dim3(768 / 128, ROWS / 128), 256, 0, stream>>>(
      yb, wt_aproj, b_aproj, x, x2, ROWS, 768, 768);
  // LN2
  ln_kernel<<<ROWS, 64, 0, stream>>>(x2, ln2_g, ln2_b, lnb);
  // h = gelu(ln2 @ w_fc + b_fc)
  gemm_kernel<1><<<dim3(3072 / 128, ROWS / 128), 256, 0, stream>>>(
      lnb, wt_fc, b_fc, nullptr, qkvb, ROWS, 3072, 768);
  // out = x2 + h @ w_mproj + b_mproj
  gemm_kernel<2><<<dim3(768 / 128, ROWS / 128), 256, 0, stream>>>(
      qkvb, wt_mproj, b_mproj, x2, (float*)d_out, ROWS, 768, 3072);
}

// Round 2
// 452.896 us; speedup vs baseline: 1.0785x; 1.0785x over previous
//
#include <hip/hip_runtime.h>
#include <hip/hip_bf16.h>

#define NE 768
#define NH 12
#define HD 64
#define BB 4
#define TT 2048
#define ROWS (BB*TT)  // 8192

typedef __attribute__((ext_vector_type(8))) short bf16x8;
typedef __attribute__((ext_vector_type(4))) float f32x4;

__device__ __forceinline__ short f2bf(float f) {
  __hip_bfloat16 h = __float2bfloat16(f);
  union { __hip_bfloat16 h; short s; } u; u.h = h; return u.s;
}

__device__ __forceinline__ void gload16(const void* g, void* l) {
  __builtin_amdgcn_global_load_lds(
      (const __attribute__((address_space(1))) void*)g,
      (__attribute__((address_space(3))) void*)l,
      16, 0, 0);
}

// ---------------- weight convert + transpose: W[K][N] f32 -> Wt[N][K] bf16 ----
__global__ __launch_bounds__(256) void wtrans_kernel(
    const float* __restrict__ W, short* __restrict__ Wt, int K, int N) {
  __shared__ short tile[64 * 65];
  int k0 = blockIdx.x * 64, n0 = blockIdx.y * 64;
  int t = threadIdx.x;
#pragma unroll
  for (int p = 0; p < 16; ++p) {
    int idx = p * 256 + t;
    int r = idx >> 6, c = idx & 63;
    tile[r * 65 + c] = f2bf(W[(size_t)(k0 + r) * N + n0 + c]);
  }
  __syncthreads();
#pragma unroll
  for (int p = 0; p < 16; ++p) {
    int idx = p * 256 + t;
    int rr = idx >> 6, cc = idx & 63;
    Wt[(size_t)(n0 + rr) * K + k0 + cc] = tile[cc * 65 + rr];
  }
}

// ---------------- LayerNorm: fp32 in -> bf16 out, one wave per row ----------
__global__ __launch_bounds__(64) void ln_kernel(
    const float* __restrict__ x, const float* __restrict__ g,
    const float* __restrict__ b, short* __restrict__ out) {
  int row = blockIdx.x, l = threadIdx.x;
  const float* xr = x + (size_t)row * NE;
  float4 v[3];
  float s = 0.f, ss = 0.f;
#pragma unroll
  for (int i = 0; i < 3; ++i) {
    v[i] = *reinterpret_cast<const float4*>(xr + l * 4 + i * 256);
    s += v[i].x + v[i].y + v[i].z + v[i].w;
    ss += v[i].x * v[i].x + v[i].y * v[i].y + v[i].z * v[i].z + v[i].w * v[i].w;
  }
#pragma unroll
  for (int m = 1; m < 64; m <<= 1) {
    s += __shfl_xor(s, m);
    ss += __shfl_xor(ss, m);
  }
  float mu = s * (1.0f / NE);
  float var = ss * (1.0f / NE) - mu * mu;
  float rstd = rsqrtf(var + 1e-5f);
#pragma unroll
  for (int i = 0; i < 3; ++i) {
    float4 gv = *reinterpret_cast<const float4*>(g + l * 4 + i * 256);
    float4 bv = *reinterpret_cast<const float4*>(b + l * 4 + i * 256);
    short4 o;
    o.x = f2bf((v[i].x - mu) * rstd * gv.x + bv.x);
    o.y = f2bf((v[i].y - mu) * rstd * gv.y + bv.y);
    o.z = f2bf((v[i].z - mu) * rstd * gv.z + bv.z);
    o.w = f2bf((v[i].w - mu) * rstd * gv.w + bv.w);
    *reinterpret_cast<short4*>(out + (size_t)row * NE + l * 4 + i * 256) = o;
  }
}

// ---------------- GEMM: C[M][N] = A[M][K](bf16) * Bt[N][K](bf16)^T + epi ----
template <int EPI>
__global__ __launch_bounds__(256) void gemm_kernel(
    const short* __restrict__ A, const short* __restrict__ Bt,
    const float* __restrict__ bias, const float* __restrict__ resid,
    void* __restrict__ Cout, int M, int N, int K) {
  __shared__ short As[128 * 32];
  __shared__ short Bs[128 * 32];
  int t = threadIdx.x;
  int w = t >> 6, l = t & 63;
  int wr = w >> 1, wc = w & 1;
  int bn = blockIdx.x, bm = blockIdx.y;
  int lr = l & 15, lkb = (l >> 4) * 8;

  f32x4 acc[4][4];
#pragma unroll
  for (int i = 0; i < 4; ++i)
#pragma unroll
    for (int j = 0; j < 4; ++j) acc[i][j] = (f32x4){0.f, 0.f, 0.f, 0.f};

  const short* ga = A + (size_t)(bm * 128 + (t >> 2)) * K + (t & 3) * 8;
  const short* gb = Bt + (size_t)(bn * 128 + (t >> 2)) * K + (t & 3) * 8;
  short* lA = As + t * 8;
  short* lB = Bs + t * 8;
  int nk = K >> 5;
  for (int kt = 0; kt < nk; ++kt) {
    __syncthreads();
    gload16(ga, lA);
    gload16(ga + (size_t)64 * K, lA + 64 * 32);
    gload16(gb, lB);
    gload16(gb + (size_t)64 * K, lB + 64 * 32);
    ga += 32; gb += 32;
    __syncthreads();
    bf16x8 af[4], bfr[4];
#pragma unroll
    for (int i = 0; i < 4; ++i)
      af[i] = *reinterpret_cast<const bf16x8*>(As + (wr * 64 + i * 16 + lr) * 32 + lkb);
#pragma unroll
    for (int j = 0; j < 4; ++j)
      bfr[j] = *reinterpret_cast<const bf16x8*>(Bs + (wc * 64 + j * 16 + lr) * 32 + lkb);
#pragma unroll
    for (int i = 0; i < 4; ++i)
#pragma unroll
      for (int j = 0; j < 4; ++j)
        acc[i][j] = __builtin_amdgcn_mfma_f32_16x16x32_bf16(af[i], bfr[j], acc[i][j], 0, 0, 0);
  }

  int rbase = bm * 128 + wr * 64;
  int cbase = bn * 128 + wc * 64;
#pragma unroll
  for (int i = 0; i < 4; ++i) {
#pragma unroll
    for (int r = 0; r < 4; ++r) {
      int row = rbase + i * 16 + (l >> 4) * 4 + r;
#pragma unroll
      for (int j = 0; j < 4; ++j) {
        int col = cbase + j * 16 + lr;
        float v = acc[i][j][r] + bias[col];
        if (EPI == 0) {
          ((short*)Cout)[(size_t)row * N + col] = f2bf(v);
        } else if (EPI == 1) {
          v = 0.5f * v * (1.0f + erff(v * 0.70710678118654752f));
          ((short*)Cout)[(size_t)row * N + col] = f2bf(v);
        } else {
          ((float*)Cout)[(size_t)row * N + col] = v + resid[(size_t)row * N + col];
        }
      }
    }
  }
}

// ---------------- causal flash attention, QBLK=128, KVBLK=64 ----------------
// qkv: [ROWS][3*NE] bf16 (q|k|v). y: [ROWS][NE] bf16.
__global__ __launch_bounds__(256) void attn_kernel(
    const short* __restrict__ qkv, short* __restrict__ y) {
  __shared__ short Ks[64 * 64];        // row-major [kpos][hd], XOR-swizzled
  __shared__ short Vt[64 * 64];        // transposed [hd][kpos], XOR-swizzled
  __shared__ short Ps[4 * 16 * 72];    // per-wave P staging, pad 72
  int t = threadIdx.x, w = t >> 6, l = t & 63;
  int lr = l & 15, g = l >> 4, lkb = g * 8;
  int qt = (gridDim.x - 1) - blockIdx.x;   // longest blocks first
  int bh = blockIdx.y;
  int b = bh / NH, h = bh % NH;
  int qbase = qt * 128;
  const int rstride = 3 * NE;

  // Q fragments (registers): rows qbase + w*32 + i*16 + lr
  bf16x8 qf[2][2];
#pragma unroll
  for (int i = 0; i < 2; ++i) {
    const short* qrow = qkv + (size_t)(b * TT + qbase + w * 32 + i * 16 + lr) * rstride + h * HD + lkb;
    qf[i][0] = *reinterpret_cast<const bf16x8*>(qrow);
    qf[i][1] = *reinterpret_cast<const bf16x8*>(qrow + 32);
  }

  f32x4 o[2][4];
  float m_run[2][4], l_run[2][4];
#pragma unroll
  for (int i = 0; i < 2; ++i)
#pragma unroll
    for (int j = 0; j < 4; ++j) {
      o[i][j] = (f32x4){0.f, 0.f, 0.f, 0.f};
      m_run[i][j] = -3e38f; l_run[i][j] = 0.f;
    }

  short* Psw = Ps + w * 16 * 72;
  // V gather assignment: this thread owns hd pair (hd2, hd2+1), rows r0v..r0v+7
  int hd2 = (t & 31) * 2;
  int r0v = (t >> 5) * 8;
  // K staging chunk ids (16B chunks of the 64x64 tile)
  int ci0 = t, ci1 = t + 256;
  int krow0 = ci0 >> 3, kc0 = ((ci0 & 7) ^ (krow0 & 7)) * 8;
  int krow1 = ci1 >> 3, kc1 = ((ci1 & 7) ^ (krow1 & 7)) * 8;

  int nkv = 2 * qt + 2;
  for (int kt = 0; kt < nkv; ++kt) {
    int kvbase = kt * 64;
    __syncthreads();   // prev compute done: Ks/Vt free
    // --- stage K (async, swizzled source -> linear LDS) ---
    gload16(qkv + (size_t)(b * TT + kvbase + krow0) * rstride + NE + h * HD + kc0, Ks + ci0 * 8);
    gload16(qkv + (size_t)(b * TT + kvbase + krow1) * rstride + NE + h * HD + kc1, Ks + ci1 * 8);
    // --- stage V transposed: 8 coalesced u32 loads -> 2 ds_write_b128 ---
    {
      unsigned int v32[8];
#pragma unroll
      for (int e = 0; e < 8; ++e)
        v32[e] = *reinterpret_cast<const unsigned int*>(
            qkv + (size_t)(b * TT + kvbase + r0v + e) * rstride + 2 * NE + h * HD + hd2);
      bf16x8 ra, rb;
#pragma unroll
      for (int e = 0; e < 8; ++e) {
        ra[e] = (short)(v32[e] & 0xffffu);
        rb[e] = (short)(v32[e] >> 16);
      }
      int ba = (hd2 * 128 + r0v * 2) ^ ((hd2 & 7) << 4);
      int bb2 = ((hd2 + 1) * 128 + r0v * 2) ^ (((hd2 + 1) & 7) << 4);
      *reinterpret_cast<bf16x8*>((char*)Vt + ba) = ra;
      *reinterpret_cast<bf16x8*>((char*)Vt + bb2) = rb;
    }
    __syncthreads();   // K landed (vmcnt drained), Vt writes visible

    // --- QK^T ---
    f32x4 s[2][4];
#pragma unroll
    for (int nt = 0; nt < 4; ++nt) {
      int row = nt * 16 + lr;
      bf16x8 kf0 = *reinterpret_cast<const bf16x8*>(
          (char*)Ks + ((row * 128 + lkb * 2) ^ ((lr & 7) << 4)));
      bf16x8 kf1 = *reinterpret_cast<const bf16x8*>(
          (char*)Ks + ((row * 128 + 64 + lkb * 2) ^ ((lr & 7) << 4)));
#pragma unroll
      for (int i = 0; i < 2; ++i) {
        f32x4 st = (f32x4){0.f, 0.f, 0.f, 0.f};
        st = __builtin_amdgcn_mfma_f32_16x16x32_bf16(qf[i][0], kf0, st, 0, 0, 0);
        st = __builtin_amdgcn_mfma_f32_16x16x32_bf16(qf[i][1], kf1, st, 0, 0, 0);
        s[i][nt] = st;
      }
    }

#pragma unroll
    for (int i = 0; i < 2; ++i) {
      int qmin = qbase + w * 32 + i * 16;
      if (kvbase > qmin + 15) continue;   // fully masked row-block (wave-uniform)
      if (kvbase + 63 > qmin) {
#pragma unroll
        for (int nt = 0; nt < 4; ++nt) {
          int kc = kvbase + nt * 16 + lr;
#pragma unroll
          for (int r = 0; r < 4; ++r)
            s[i][nt][r] = (kc <= qmin + g * 4 + r) ? s[i][nt][r] * 0.125f : -3e38f;
        }
      } else {
#pragma unroll
        for (int nt = 0; nt < 4; ++nt)
#pragma unroll
          for (int r = 0; r < 4; ++r)
            s[i][nt][r] *= 0.125f;
      }
      // --- online softmax (16-lane row groups) ---
#pragma unroll
      for (int r = 0; r < 4; ++r) {
        float mb = fmaxf(fmaxf(s[i][0][r], s[i][1][r]), fmaxf(s[i][2][r], s[i][3][r]));
        mb = fmaxf(mb, __shfl_xor(mb, 1));
        mb = fmaxf(mb, __shfl_xor(mb, 2));
        mb = fmaxf(mb, __shfl_xor(mb, 4));
        mb = fmaxf(mb, __shfl_xor(mb, 8));
        float mn = fmaxf(m_run[i][r], mb);
        float al = __expf(m_run[i][r] - mn);
        m_run[i][r] = mn;
        float rs = 0.f;
#pragma unroll
        for (int nt = 0; nt < 4; ++nt) {
          float p = __expf(s[i][nt][r] - mn);
          s[i][nt][r] = p;
          rs += p;
        }
        rs += __shfl_xor(rs, 1);
        rs += __shfl_xor(rs, 2);
        rs += __shfl_xor(rs, 4);
        rs += __shfl_xor(rs, 8);
        l_run[i][r] = l_run[i][r] * al + rs;
#pragma unroll
        for (int j = 0; j < 4; ++j) o[i][j][r] *= al;
      }
      // --- P -> wave-private LDS (bf16) ---
#pragma unroll
      for (int nt = 0; nt < 4; ++nt)
#pragma unroll
        for (int r = 0; r < 4; ++r)
          Psw[(g * 4 + r) * 72 + nt * 16 + lr] = f2bf(s[i][nt][r]);
      // --- PV ---
      bf16x8 pf0 = *reinterpret_cast<const bf16x8*>(Psw + lr * 72 + lkb);
      bf16x8 pf1 = *reinterpret_cast<const bf16x8*>(Psw + lr * 72 + 32 + lkb);
#pragma unroll
      for (int j = 0; j < 4; ++j) {
        int vrow = j * 16 + lr;
        bf16x8 vf0 = *reinterpret_cast<const bf16x8*>(
            (char*)Vt + ((vrow * 128 + lkb * 2) ^ ((lr & 7) << 4)));
        bf16x8 vf1 = *reinterpret_cast<const bf16x8*>(
            (char*)Vt + ((vrow * 128 + 64 + lkb * 2) ^ ((lr & 7) << 4)));
        o[i][j] = __builtin_amdgcn_mfma_f32_16x16x32_bf16(pf0, vf0, o[i][j], 0, 0, 0);
        o[i][j] = __builtin_amdgcn_mfma_f32_16x16x32_bf16(pf1, vf1, o[i][j], 0, 0, 0);
      }
    }
  }

#pragma unroll
  for (int i = 0; i < 2; ++i)
#pragma unroll
    for (int r = 0; r < 4; ++r) {
      float inv = 1.0f / l_run[i][r];
      size_t row = (size_t)(b * TT + qbase + w * 32 + i * 16 + g * 4 + r);
#pragma unroll
      for (int j = 0; j < 4; ++j)
        y[row * NE + h * HD + j * 16 + lr] = f2bf(o[i][j][r] * inv);
    }
}

extern "C" void kernel_launch(void* const* d_in, const int* in_sizes, int n_in,
                              void* d_out, int out_size, void* d_ws, size_t ws_size,
                              hipStream_t stream) {
  (void)in_sizes; (void)n_in; (void)out_size; (void)ws_size;
  const float* x       = (const float*)d_in[0];
  const float* ln1_g   = (const float*)d_in[1];
  const float* ln1_b   = (const float*)d_in[2];
  const float* w_attn  = (const float*)d_in[3];
  const float* b_attn  = (const float*)d_in[4];
  const float* w_aproj = (const float*)d_in[5];
  const float* b_aproj = (const float*)d_in[6];
  const float* ln2_g   = (const float*)d_in[7];
  const float* ln2_b   = (const float*)d_in[8];
  const float* w_fc    = (const float*)d_in[9];
  const float* b_fc    = (const float*)d_in[10];
  const float* w_mproj = (const float*)d_in[11];
  const float* b_mproj = (const float*)d_in[12];

  char* ws = (char*)d_ws;
  size_t off = 0;
  auto alloc = [&](size_t bytes) {
    char* p = ws + off;
    off += (bytes + 255) & ~(size_t)255;
    return p;
  };
  short* wt_attn  = (short*)alloc((size_t)2304 * 768 * 2);
  short* wt_aproj = (short*)alloc((size_t)768 * 768 * 2);
  short* wt_fc    = (short*)alloc((size_t)3072 * 768 * 2);
  short* wt_mproj = (short*)alloc((size_t)768 * 3072 * 2);
  short* lnb  = (short*)alloc((size_t)ROWS * 768 * 2);
  short* qkvb = (short*)alloc((size_t)ROWS * 3072 * 2);
  short* yb   = (short*)alloc((size_t)ROWS * 768 * 2);
  float* x2   = (float*)alloc((size_t)ROWS * 768 * 4);

  wtrans_kernel<<<dim3(768 / 64, 2304 / 64), 256, 0, stream>>>(w_attn, wt_attn, 768, 2304);
  wtrans_kernel<<<dim3(768 / 64, 768 / 64), 256, 0, stream>>>(w_aproj, wt_aproj, 768, 768);
  wtrans_kernel<<<dim3(768 / 64, 3072 / 64), 256, 0, stream>>>(w_fc, wt_fc, 768, 3072);
  wtrans_kernel<<<dim3(3072 / 64, 768 / 64), 256, 0, stream>>>(w_mproj, wt_mproj, 3072, 768);

  ln_kernel<<<ROWS, 64, 0, stream>>>(x, ln1_g, ln1_b, lnb);
  gemm_kernel<0><<<dim3(2304 / 128, ROWS / 128), 256, 0, stream>>>(
      lnb, wt_attn, b_attn, nullptr, qkvb, ROWS, 2304, 768);
  attn_kernel<<<dim3(TT / 128, BB * NH), 256, 0, stream>>>(qkvb, yb);
  gemm_kernel<2><<<dim3(768 / 128, ROWS / 128), 256, 0, stream>>>(
      yb, wt_aproj, b_aproj, x, x2, ROWS, 768, 768);
  ln_kernel<<<ROWS, 64, 0, stream>>>(x2, ln2_g, ln2_b, lnb);
  gemm_kernel<1><<<dim3(3072 / 128, ROWS / 128), 256, 0, stream>>>(
      lnb, wt_fc, b_fc, nullptr, qkvb, ROWS, 3072, 768);
  gemm_kernel<2><<<dim3(768 / 128, ROWS / 128), 256, 0, stream>>>(
      qkvb, wt_mproj, b_mproj, x2, (float*)d_out, ROWS, 768, 3072);
}

// Round 3
// 421.170 us; speedup vs baseline: 1.1597x; 1.0753x over previous
//
#include <hip/hip_runtime.h>
#include <hip/hip_bf16.h>

#define NE 768
#define NH 12
#define HD 64
#define BB 4
#define TT 2048
#define ROWS (BB*TT)  // 8192

typedef __attribute__((ext_vector_type(8))) short bf16x8;
typedef __attribute__((ext_vector_type(4))) float f32x4;

__device__ __forceinline__ short f2bf(float f) {
  __hip_bfloat16 h = __float2bfloat16(f);
  union { __hip_bfloat16 h; short s; } u; u.h = h; return u.s;
}

__device__ __forceinline__ void gload16(const void* g, void* l) {
  __builtin_amdgcn_global_load_lds(
      (const __attribute__((address_space(1))) void*)g,
      (__attribute__((address_space(3))) void*)l,
      16, 0, 0);
}

// ---------------- weight convert + transpose: W[K][N] f32 -> Wt[N][K] bf16 ----
__global__ __launch_bounds__(256) void wtrans_kernel(
    const float* __restrict__ W, short* __restrict__ Wt, int K, int N) {
  __shared__ short tile[64 * 65];
  int k0 = blockIdx.x * 64, n0 = blockIdx.y * 64;
  int t = threadIdx.x;
#pragma unroll
  for (int p = 0; p < 16; ++p) {
    int idx = p * 256 + t;
    int r = idx >> 6, c = idx & 63;
    tile[r * 65 + c] = f2bf(W[(size_t)(k0 + r) * N + n0 + c]);
  }
  __syncthreads();
#pragma unroll
  for (int p = 0; p < 16; ++p) {
    int idx = p * 256 + t;
    int rr = idx >> 6, cc = idx & 63;
    Wt[(size_t)(n0 + rr) * K + k0 + cc] = tile[cc * 65 + rr];
  }
}

// ---------------- LayerNorm: fp32 in -> bf16 out, one wave per row ----------
__global__ __launch_bounds__(64) void ln_kernel(
    const float* __restrict__ x, const float* __restrict__ g,
    const float* __restrict__ b, short* __restrict__ out) {
  int row = blockIdx.x, l = threadIdx.x;
  const float* xr = x + (size_t)row * NE;
  float4 v[3];
  float s = 0.f, ss = 0.f;
#pragma unroll
  for (int i = 0; i < 3; ++i) {
    v[i] = *reinterpret_cast<const float4*>(xr + l * 4 + i * 256);
    s += v[i].x + v[i].y + v[i].z + v[i].w;
    ss += v[i].x * v[i].x + v[i].y * v[i].y + v[i].z * v[i].z + v[i].w * v[i].w;
  }
#pragma unroll
  for (int m = 1; m < 64; m <<= 1) {
    s += __shfl_xor(s, m);
    ss += __shfl_xor(ss, m);
  }
  float mu = s * (1.0f / NE);
  float var = ss * (1.0f / NE) - mu * mu;
  float rstd = rsqrtf(var + 1e-5f);
#pragma unroll
  for (int i = 0; i < 3; ++i) {
    float4 gv = *reinterpret_cast<const float4*>(g + l * 4 + i * 256);
    float4 bv = *reinterpret_cast<const float4*>(b + l * 4 + i * 256);
    short4 o;
    o.x = f2bf((v[i].x - mu) * rstd * gv.x + bv.x);
    o.y = f2bf((v[i].y - mu) * rstd * gv.y + bv.y);
    o.z = f2bf((v[i].z - mu) * rstd * gv.z + bv.z);
    o.w = f2bf((v[i].w - mu) * rstd * gv.w + bv.w);
    *reinterpret_cast<short4*>(out + (size_t)row * NE + l * 4 + i * 256) = o;
  }
}

// ---------------- GEMM 128x128: C = A[M][K] * Bt[N][K]^T + epi --------------
template <int EPI>
__global__ __launch_bounds__(256) void gemm_kernel(
    const short* __restrict__ A, const short* __restrict__ Bt,
    const float* __restrict__ bias, const float* __restrict__ resid,
    void* __restrict__ Cout, int M, int N, int K) {
  __shared__ short As[128 * 32];
  __shared__ short Bs[128 * 32];
  int t = threadIdx.x;
  int w = t >> 6, l = t & 63;
  int wr = w >> 1, wc = w & 1;
  int bn = blockIdx.x, bm = blockIdx.y;
  int lr = l & 15, lkb = (l >> 4) * 8;

  f32x4 acc[4][4];
#pragma unroll
  for (int i = 0; i < 4; ++i)
#pragma unroll
    for (int j = 0; j < 4; ++j) acc[i][j] = (f32x4){0.f, 0.f, 0.f, 0.f};

  const short* ga = A + (size_t)(bm * 128 + (t >> 2)) * K + (t & 3) * 8;
  const short* gb = Bt + (size_t)(bn * 128 + (t >> 2)) * K + (t & 3) * 8;
  short* lA = As + t * 8;
  short* lB = Bs + t * 8;
  int nk = K >> 5;
  for (int kt = 0; kt < nk; ++kt) {
    __syncthreads();
    gload16(ga, lA);
    gload16(ga + (size_t)64 * K, lA + 64 * 32);
    gload16(gb, lB);
    gload16(gb + (size_t)64 * K, lB + 64 * 32);
    ga += 32; gb += 32;
    __syncthreads();
    bf16x8 af[4], bfr[4];
#pragma unroll
    for (int i = 0; i < 4; ++i)
      af[i] = *reinterpret_cast<const bf16x8*>(As + (wr * 64 + i * 16 + lr) * 32 + lkb);
#pragma unroll
    for (int j = 0; j < 4; ++j)
      bfr[j] = *reinterpret_cast<const bf16x8*>(Bs + (wc * 64 + j * 16 + lr) * 32 + lkb);
#pragma unroll
    for (int i = 0; i < 4; ++i)
#pragma unroll
      for (int j = 0; j < 4; ++j)
        acc[i][j] = __builtin_amdgcn_mfma_f32_16x16x32_bf16(af[i], bfr[j], acc[i][j], 0, 0, 0);
  }

  int rbase = bm * 128 + wr * 64;
  int cbase = bn * 128 + wc * 64;
#pragma unroll
  for (int i = 0; i < 4; ++i) {
#pragma unroll
    for (int r = 0; r < 4; ++r) {
      int row = rbase + i * 16 + (l >> 4) * 4 + r;
#pragma unroll
      for (int j = 0; j < 4; ++j) {
        int col = cbase + j * 16 + lr;
        float v = acc[i][j][r] + bias[col];
        if (EPI == 0) {
          ((short*)Cout)[(size_t)row * N + col] = f2bf(v);
        } else if (EPI == 1) {
          v = 0.5f * v * (1.0f + erff(v * 0.70710678118654752f));
          ((short*)Cout)[(size_t)row * N + col] = f2bf(v);
        } else {
          ((float*)Cout)[(size_t)row * N + col] = v + resid[(size_t)row * N + col];
        }
      }
    }
  }
}

// ---------------- GEMM 128x64 (for thin-N): 4 waves x (32 rows x 64 cols) ---
template <int EPI>
__global__ __launch_bounds__(256) void gemm64_kernel(
    const short* __restrict__ A, const short* __restrict__ Bt,
    const float* __restrict__ bias, const float* __restrict__ resid,
    void* __restrict__ Cout, int M, int N, int K) {
  __shared__ short As[128 * 32];
  __shared__ short Bs[64 * 32];
  int t = threadIdx.x;
  int w = t >> 6, l = t & 63;
  int bn = blockIdx.x, bm = blockIdx.y;
  int lr = l & 15, lkb = (l >> 4) * 8;

  f32x4 acc[2][4];
#pragma unroll
  for (int i = 0; i < 2; ++i)
#pragma unroll
    for (int j = 0; j < 4; ++j) acc[i][j] = (f32x4){0.f, 0.f, 0.f, 0.f};

  const short* ga = A + (size_t)(bm * 128 + (t >> 2)) * K + (t & 3) * 8;
  const short* gb = Bt + (size_t)(bn * 64 + (t >> 2)) * K + (t & 3) * 8;
  short* lA = As + t * 8;
  short* lB = Bs + t * 8;  // 256 threads x 16B = 64 rows x 32
  int nk = K >> 5;
  for (int kt = 0; kt < nk; ++kt) {
    __syncthreads();
    gload16(ga, lA);
    gload16(ga + (size_t)64 * K, lA + 64 * 32);
    gload16(gb, lB);
    ga += 32; gb += 32;
    __syncthreads();
    bf16x8 af[2], bfr[4];
#pragma unroll
    for (int i = 0; i < 2; ++i)
      af[i] = *reinterpret_cast<const bf16x8*>(As + (w * 32 + i * 16 + lr) * 32 + lkb);
#pragma unroll
    for (int j = 0; j < 4; ++j)
      bfr[j] = *reinterpret_cast<const bf16x8*>(Bs + (j * 16 + lr) * 32 + lkb);
#pragma unroll
    for (int i = 0; i < 2; ++i)
#pragma unroll
      for (int j = 0; j < 4; ++j)
        acc[i][j] = __builtin_amdgcn_mfma_f32_16x16x32_bf16(af[i], bfr[j], acc[i][j], 0, 0, 0);
  }

  int rbase = bm * 128 + w * 32;
  int cbase = bn * 64;
#pragma unroll
  for (int i = 0; i < 2; ++i) {
#pragma unroll
    for (int r = 0; r < 4; ++r) {
      int row = rbase + i * 16 + (l >> 4) * 4 + r;
#pragma unroll
      for (int j = 0; j < 4; ++j) {
        int col = cbase + j * 16 + lr;
        float v = acc[i][j][r] + bias[col];
        if (EPI == 0) {
          ((short*)Cout)[(size_t)row * N + col] = f2bf(v);
        } else if (EPI == 1) {
          v = 0.5f * v * (1.0f + erff(v * 0.70710678118654752f));
          ((short*)Cout)[(size_t)row * N + col] = f2bf(v);
        } else {
          ((float*)Cout)[(size_t)row * N + col] = v + resid[(size_t)row * N + col];
        }
      }
    }
  }
}

// ---------------- causal flash attention, QBLK=64, KVBLK=64, double-buffered -
// qkv: [ROWS][3*NE] bf16 (q|k|v). y: [ROWS][NE] bf16.
__global__ __launch_bounds__(256) void attn_kernel(
    const short* __restrict__ qkv, short* __restrict__ y) {
  __shared__ short Ks[2][64 * 64];   // [kpos][hd], XOR-swizzled
  __shared__ short Vt[2][64 * 64];   // [hd][kpos], XOR-swizzled
  __shared__ short Ps[4][16 * 72];   // per-wave P staging
  int t = threadIdx.x, w = t >> 6, l = t & 63;
  int lr = l & 15, g = l >> 4, lkb = g * 8;
  int qt = (gridDim.x - 1) - blockIdx.x;   // longest blocks first
  int bh = blockIdx.y;
  int b = bh / NH, h = bh % NH;
  int qbase = qt * 64;
  const int rstride = 3 * NE;

  // Q fragments: rows qbase + w*16 + lr
  const short* qrow = qkv + (size_t)(b * TT + qbase + w * 16 + lr) * rstride + h * HD + lkb;
  bf16x8 qf0 = *reinterpret_cast<const bf16x8*>(qrow);
  bf16x8 qf1 = *reinterpret_cast<const bf16x8*>(qrow + 32);

  f32x4 o[4];
  float m_run[4], l_run[4];
#pragma unroll
  for (int j = 0; j < 4; ++j) {
    o[j] = (f32x4){0.f, 0.f, 0.f, 0.f};
    m_run[j] = -3e38f; l_run[j] = 0.f;
  }

  short* Psw = Ps[w];
  // staging geometry
  int hd2 = (t & 31) * 2;            // V: this thread owns hd pair
  int r0v = (t >> 5) * 8;            //    rows r0v..r0v+7
  int ci0 = t, ci1 = t + 256;        // K: 16B chunk ids
  int krow0 = ci0 >> 3, kc0 = ((ci0 & 7) ^ (krow0 & 7)) * 8;
  int krow1 = ci1 >> 3, kc1 = ((ci1 & 7) ^ (krow1 & 7)) * 8;
  int vba = (hd2 * 128 + r0v * 2) ^ ((hd2 & 7) << 4);
  int vbb = ((hd2 + 1) * 128 + r0v * 2) ^ (((hd2 + 1) & 7) << 4);

  const short* kvb = qkv + (size_t)(b * TT) * rstride + h * HD;

  unsigned int v32[8];
  // --- prologue: fully stage tile 0 into buffer 0 ---
  {
#pragma unroll
    for (int e = 0; e < 8; ++e)
      v32[e] = *reinterpret_cast<const unsigned int*>(
          kvb + (size_t)(r0v + e) * rstride + 2 * NE + hd2);
    gload16(kvb + (size_t)krow0 * rstride + NE + kc0, &Ks[0][ci0 * 8]);
    gload16(kvb + (size_t)krow1 * rstride + NE + kc1, &Ks[0][ci1 * 8]);
    bf16x8 ra, rb;
#pragma unroll
    for (int e = 0; e < 8; ++e) {
      ra[e] = (short)(v32[e] & 0xffffu);
      rb[e] = (short)(v32[e] >> 16);
    }
    *reinterpret_cast<bf16x8*>((char*)Vt[0] + vba) = ra;
    *reinterpret_cast<bf16x8*>((char*)Vt[0] + vbb) = rb;
  }

  int nkv = qt + 1;
  int qmin = qbase + w * 16;
  for (int kt = 0; kt < nkv; ++kt) {
    int bi = kt & 1;
    int kvbase = kt * 64;
    bool pre = (kt + 1 < nkv);
    __syncthreads();   // buf bi ready (gload drained, V writes visible)

    if (pre) {   // issue next tile's loads (latency hides under compute)
      const short* nb = kvb + (size_t)(kvbase + 64) * rstride;
#pragma unroll
      for (int e = 0; e < 8; ++e)
        v32[e] = *reinterpret_cast<const unsigned int*>(
            nb + (size_t)(r0v + e) * rstride + 2 * NE + hd2);
      gload16(nb + (size_t)krow0 * rstride + NE + kc0, &Ks[bi ^ 1][ci0 * 8]);
      gload16(nb + (size_t)krow1 * rstride + NE + kc1, &Ks[bi ^ 1][ci1 * 8]);
    }

    // --- QK^T ---
    f32x4 s[4];
#pragma unroll
    for (int nt = 0; nt < 4; ++nt) {
      int row = nt * 16 + lr;
      bf16x8 kf0 = *reinterpret_cast<const bf16x8*>(
          (char*)Ks[bi] + ((row * 128 + lkb * 2) ^ ((lr & 7) << 4)));
      bf16x8 kf1 = *reinterpret_cast<const bf16x8*>(
          (char*)Ks[bi] + ((row * 128 + 64 + lkb * 2) ^ ((lr & 7) << 4)));
      f32x4 st = (f32x4){0.f, 0.f, 0.f, 0.f};
      st = __builtin_amdgcn_mfma_f32_16x16x32_bf16(qf0, kf0, st, 0, 0, 0);
      st = __builtin_amdgcn_mfma_f32_16x16x32_bf16(qf1, kf1, st, 0, 0, 0);
      s[nt] = st;
    }

    // --- mask/scale ---
    if (kvbase + 63 > qmin) {   // diagonal tile
#pragma unroll
      for (int nt = 0; nt < 4; ++nt) {
        int kc = kvbase + nt * 16 + lr;
#pragma unroll
        for (int r = 0; r < 4; ++r)
          s[nt][r] = (kc <= qmin + g * 4 + r) ? s[nt][r] * 0.125f : -3e38f;
      }
    } else {
#pragma unroll
      for (int nt = 0; nt < 4; ++nt)
#pragma unroll
        for (int r = 0; r < 4; ++r)
          s[nt][r] *= 0.125f;
    }

    // --- online softmax (16-lane row groups) ---
#pragma unroll
    for (int r = 0; r < 4; ++r) {
      float mb = fmaxf(fmaxf(s[0][r], s[1][r]), fmaxf(s[2][r], s[3][r]));
      mb = fmaxf(mb, __shfl_xor(mb, 1));
      mb = fmaxf(mb, __shfl_xor(mb, 2));
      mb = fmaxf(mb, __shfl_xor(mb, 4));
      mb = fmaxf(mb, __shfl_xor(mb, 8));
      float mn = fmaxf(m_run[r], mb);
      float al = __expf(m_run[r] - mn);
      m_run[r] = mn;
      float rs = 0.f;
#pragma unroll
      for (int nt = 0; nt < 4; ++nt) {
        float p = __expf(s[nt][r] - mn);
        s[nt][r] = p;
        rs += p;
      }
      rs += __shfl_xor(rs, 1);
      rs += __shfl_xor(rs, 2);
      rs += __shfl_xor(rs, 4);
      rs += __shfl_xor(rs, 8);
      l_run[r] = l_run[r] * al + rs;
#pragma unroll
      for (int j = 0; j < 4; ++j) o[j][r] *= al;
    }

    // --- P -> wave-private LDS (bf16) ---
#pragma unroll
    for (int nt = 0; nt < 4; ++nt)
#pragma unroll
      for (int r = 0; r < 4; ++r)
        Psw[(g * 4 + r) * 72 + nt * 16 + lr] = f2bf(s[nt][r]);

    // --- PV ---
    bf16x8 pf0 = *reinterpret_cast<const bf16x8*>(Psw + lr * 72 + lkb);
    bf16x8 pf1 = *reinterpret_cast<const bf16x8*>(Psw + lr * 72 + 32 + lkb);
#pragma unroll
    for (int j = 0; j < 4; ++j) {
      int vrow = j * 16 + lr;
      bf16x8 vf0 = *reinterpret_cast<const bf16x8*>(
          (char*)Vt[bi] + ((vrow * 128 + lkb * 2) ^ ((lr & 7) << 4)));
      bf16x8 vf1 = *reinterpret_cast<const bf16x8*>(
          (char*)Vt[bi] + ((vrow * 128 + 64 + lkb * 2) ^ ((lr & 7) << 4)));
      o[j] = __builtin_amdgcn_mfma_f32_16x16x32_bf16(pf0, vf0, o[j], 0, 0, 0);
      o[j] = __builtin_amdgcn_mfma_f32_16x16x32_bf16(pf1, vf1, o[j], 0, 0, 0);
    }

    // --- finish next-tile V staging: extract + swizzled LDS write ---
    if (pre) {
      bf16x8 ra, rb;
#pragma unroll
      for (int e = 0; e < 8; ++e) {
        ra[e] = (short)(v32[e] & 0xffffu);
        rb[e] = (short)(v32[e] >> 16);
      }
      *reinterpret_cast<bf16x8*>((char*)Vt[bi ^ 1] + vba) = ra;
      *reinterpret_cast<bf16x8*>((char*)Vt[bi ^ 1] + vbb) = rb;
    }
  }

#pragma unroll
  for (int r = 0; r < 4; ++r) {
    float inv = 1.0f / l_run[r];
    size_t row = (size_t)(b * TT + qbase + w * 16 + g * 4 + r);
#pragma unroll
    for (int j = 0; j < 4; ++j)
      y[row * NE + h * HD + j * 16 + lr] = f2bf(o[j][r] * inv);
  }
}

extern "C" void kernel_launch(void* const* d_in, const int* in_sizes, int n_in,
                              void* d_out, int out_size, void* d_ws, size_t ws_size,
                              hipStream_t stream) {
  (void)in_sizes; (void)n_in; (void)out_size; (void)ws_size;
  const float* x       = (const float*)d_in[0];
  const float* ln1_g   = (const float*)d_in[1];
  const float* ln1_b   = (const float*)d_in[2];
  const float* w_attn  = (const float*)d_in[3];
  const float* b_attn  = (const float*)d_in[4];
  const float* w_aproj = (const float*)d_in[5];
  const float* b_aproj = (const float*)d_in[6];
  const float* ln2_g   = (const float*)d_in[7];
  const float* ln2_b   = (const float*)d_in[8];
  const float* w_fc    = (const float*)d_in[9];
  const float* b_fc    = (const float*)d_in[10];
  const float* w_mproj = (const float*)d_in[11];
  const float* b_mproj = (const float*)d_in[12];

  char* ws = (char*)d_ws;
  size_t off = 0;
  auto alloc = [&](size_t bytes) {
    char* p = ws + off;
    off += (bytes + 255) & ~(size_t)255;
    return p;
  };
  short* wt_attn  = (short*)alloc((size_t)2304 * 768 * 2);
  short* wt_aproj = (short*)alloc((size_t)768 * 768 * 2);
  short* wt_fc    = (short*)alloc((size_t)3072 * 768 * 2);
  short* wt_mproj = (short*)alloc((size_t)768 * 3072 * 2);
  short* lnb  = (short*)alloc((size_t)ROWS * 768 * 2);
  short* qkvb = (short*)alloc((size_t)ROWS * 3072 * 2);
  short* yb   = (short*)alloc((size_t)ROWS * 768 * 2);
  float* x2   = (float*)alloc((size_t)ROWS * 768 * 4);

  wtrans_kernel<<<dim3(768 / 64, 2304 / 64), 256, 0, stream>>>(w_attn, wt_attn, 768, 2304);
  wtrans_kernel<<<dim3(768 / 64, 768 / 64), 256, 0, stream>>>(w_aproj, wt_aproj, 768, 768);
  wtrans_kernel<<<dim3(768 / 64, 3072 / 64), 256, 0, stream>>>(w_fc, wt_fc, 768, 3072);
  wtrans_kernel<<<dim3(3072 / 64, 768 / 64), 256, 0, stream>>>(w_mproj, wt_mproj, 3072, 768);

  ln_kernel<<<ROWS, 64, 0, stream>>>(x, ln1_g, ln1_b, lnb);
  gemm_kernel<0><<<dim3(2304 / 128, ROWS / 128), 256, 0, stream>>>(
      lnb, wt_attn, b_attn, nullptr, qkvb, ROWS, 2304, 768);
  attn_kernel<<<dim3(TT / 64, BB * NH), 256, 0, stream>>>(qkvb, yb);
  gemm64_kernel<2><<<dim3(768 / 64, ROWS / 128), 256, 0, stream>>>(
      yb, wt_aproj, b_aproj, x, x2, ROWS, 768, 768);
  ln_kernel<<<ROWS, 64, 0, stream>>>(x2, ln2_g, ln2_b, lnb);
  gemm_kernel<1><<<dim3(3072 / 128, ROWS / 128), 256, 0, stream>>>(
      lnb, wt_fc, b_fc, nullptr, qkvb, ROWS, 3072, 768);
  gemm64_kernel<2><<<dim3(768 / 64, ROWS / 128), 256, 0, stream>>>(
      qkvb, wt_mproj, b_mproj, x2, (float*)d_out, ROWS, 768, 3072);
}

// Round 4
// 382.691 us; speedup vs baseline: 1.2763x; 1.1005x over previous
//
#include <hip/hip_runtime.h>
#include <hip/hip_bf16.h>

#define NE 768
#define NH 12
#define HD 64
#define BB 4
#define TT 2048
#define ROWS (BB*TT)  // 8192

typedef __attribute__((ext_vector_type(8))) short bf16x8;
typedef __attribute__((ext_vector_type(4))) float f32x4;

__device__ __forceinline__ short f2bf(float f) {
  __hip_bfloat16 h = __float2bfloat16(f);
  union { __hip_bfloat16 h; short s; } u; u.h = h; return u.s;
}

__device__ __forceinline__ void gload16(const void* g, void* l) {
  __builtin_amdgcn_global_load_lds(
      (const __attribute__((address_space(1))) void*)g,
      (__attribute__((address_space(3))) void*)l,
      16, 0, 0);
}

// ---------------- weight convert + transpose: W[K][N] f32 -> Wt[N][K] bf16 ----
__global__ __launch_bounds__(256) void wtrans_kernel(
    const float* __restrict__ W, short* __restrict__ Wt, int K, int N) {
  __shared__ short tile[64 * 65];
  int k0 = blockIdx.x * 64, n0 = blockIdx.y * 64;
  int t = threadIdx.x;
#pragma unroll
  for (int p = 0; p < 16; ++p) {
    int idx = p * 256 + t;
    int r = idx >> 6, c = idx & 63;
    tile[r * 65 + c] = f2bf(W[(size_t)(k0 + r) * N + n0 + c]);
  }
  __syncthreads();
#pragma unroll
  for (int p = 0; p < 16; ++p) {
    int idx = p * 256 + t;
    int rr = idx >> 6, cc = idx & 63;
    Wt[(size_t)(n0 + rr) * K + k0 + cc] = tile[cc * 65 + rr];
  }
}

// ---------------- LayerNorm: fp32 in -> bf16 out, one wave per row ----------
__global__ __launch_bounds__(64) void ln_kernel(
    const float* __restrict__ x, const float* __restrict__ g,
    const float* __restrict__ b, short* __restrict__ out) {
  int row = blockIdx.x, l = threadIdx.x;
  const float* xr = x + (size_t)row * NE;
  float4 v[3];
  float s = 0.f, ss = 0.f;
#pragma unroll
  for (int i = 0; i < 3; ++i) {
    v[i] = *reinterpret_cast<const float4*>(xr + l * 4 + i * 256);
    s += v[i].x + v[i].y + v[i].z + v[i].w;
    ss += v[i].x * v[i].x + v[i].y * v[i].y + v[i].z * v[i].z + v[i].w * v[i].w;
  }
#pragma unroll
  for (int m = 1; m < 64; m <<= 1) {
    s += __shfl_xor(s, m);
    ss += __shfl_xor(ss, m);
  }
  float mu = s * (1.0f / NE);
  float var = ss * (1.0f / NE) - mu * mu;
  float rstd = rsqrtf(var + 1e-5f);
#pragma unroll
  for (int i = 0; i < 3; ++i) {
    float4 gv = *reinterpret_cast<const float4*>(g + l * 4 + i * 256);
    float4 bv = *reinterpret_cast<const float4*>(b + l * 4 + i * 256);
    short4 o;
    o.x = f2bf((v[i].x - mu) * rstd * gv.x + bv.x);
    o.y = f2bf((v[i].y - mu) * rstd * gv.y + bv.y);
    o.z = f2bf((v[i].z - mu) * rstd * gv.z + bv.z);
    o.w = f2bf((v[i].w - mu) * rstd * gv.w + bv.w);
    *reinterpret_cast<short4*>(out + (size_t)row * NE + l * 4 + i * 256) = o;
  }
}

// ---------------- GEMM 128x128: C = A[M][K] * Bt[N][K]^T + epi --------------
template <int EPI>
__global__ __launch_bounds__(256) void gemm_kernel(
    const short* __restrict__ A, const short* __restrict__ Bt,
    const float* __restrict__ bias, const float* __restrict__ resid,
    void* __restrict__ Cout, int M, int N, int K) {
  __shared__ short As[128 * 32];
  __shared__ short Bs[128 * 32];
  int t = threadIdx.x;
  int w = t >> 6, l = t & 63;
  int wr = w >> 1, wc = w & 1;
  int bn = blockIdx.x, bm = blockIdx.y;
  int lr = l & 15, lkb = (l >> 4) * 8;

  f32x4 acc[4][4];
#pragma unroll
  for (int i = 0; i < 4; ++i)
#pragma unroll
    for (int j = 0; j < 4; ++j) acc[i][j] = (f32x4){0.f, 0.f, 0.f, 0.f};

  const short* ga = A + (size_t)(bm * 128 + (t >> 2)) * K + (t & 3) * 8;
  const short* gb = Bt + (size_t)(bn * 128 + (t >> 2)) * K + (t & 3) * 8;
  short* lA = As + t * 8;
  short* lB = Bs + t * 8;
  int nk = K >> 5;
  for (int kt = 0; kt < nk; ++kt) {
    __syncthreads();
    gload16(ga, lA);
    gload16(ga + (size_t)64 * K, lA + 64 * 32);
    gload16(gb, lB);
    gload16(gb + (size_t)64 * K, lB + 64 * 32);
    ga += 32; gb += 32;
    __syncthreads();
    bf16x8 af[4], bfr[4];
#pragma unroll
    for (int i = 0; i < 4; ++i)
      af[i] = *reinterpret_cast<const bf16x8*>(As + (wr * 64 + i * 16 + lr) * 32 + lkb);
#pragma unroll
    for (int j = 0; j < 4; ++j)
      bfr[j] = *reinterpret_cast<const bf16x8*>(Bs + (wc * 64 + j * 16 + lr) * 32 + lkb);
#pragma unroll
    for (int i = 0; i < 4; ++i)
#pragma unroll
      for (int j = 0; j < 4; ++j)
        acc[i][j] = __builtin_amdgcn_mfma_f32_16x16x32_bf16(af[i], bfr[j], acc[i][j], 0, 0, 0);
  }

  int rbase = bm * 128 + wr * 64;
  int cbase = bn * 128 + wc * 64;
#pragma unroll
  for (int i = 0; i < 4; ++i) {
#pragma unroll
    for (int r = 0; r < 4; ++r) {
      int row = rbase + i * 16 + (l >> 4) * 4 + r;
#pragma unroll
      for (int j = 0; j < 4; ++j) {
        int col = cbase + j * 16 + lr;
        float v = acc[i][j][r] + bias[col];
        if (EPI == 0) {
          ((short*)Cout)[(size_t)row * N + col] = f2bf(v);
        } else if (EPI == 1) {
          v = 0.5f * v * (1.0f + erff(v * 0.70710678118654752f));
          ((short*)Cout)[(size_t)row * N + col] = f2bf(v);
        } else {
          ((float*)Cout)[(size_t)row * N + col] = v + resid[(size_t)row * N + col];
        }
      }
    }
  }
}

// ---------------- GEMM 128x64 (for thin-N): 4 waves x (32 rows x 64 cols) ---
template <int EPI>
__global__ __launch_bounds__(256) void gemm64_kernel(
    const short* __restrict__ A, const short* __restrict__ Bt,
    const float* __restrict__ bias, const float* __restrict__ resid,
    void* __restrict__ Cout, int M, int N, int K) {
  __shared__ short As[128 * 32];
  __shared__ short Bs[64 * 32];
  int t = threadIdx.x;
  int w = t >> 6, l = t & 63;
  int bn = blockIdx.x, bm = blockIdx.y;
  int lr = l & 15, lkb = (l >> 4) * 8;

  f32x4 acc[2][4];
#pragma unroll
  for (int i = 0; i < 2; ++i)
#pragma unroll
    for (int j = 0; j < 4; ++j) acc[i][j] = (f32x4){0.f, 0.f, 0.f, 0.f};

  const short* ga = A + (size_t)(bm * 128 + (t >> 2)) * K + (t & 3) * 8;
  const short* gb = Bt + (size_t)(bn * 64 + (t >> 2)) * K + (t & 3) * 8;
  short* lA = As + t * 8;
  short* lB = Bs + t * 8;  // 256 threads x 16B = 64 rows x 32
  int nk = K >> 5;
  for (int kt = 0; kt < nk; ++kt) {
    __syncthreads();
    gload16(ga, lA);
    gload16(ga + (size_t)64 * K, lA + 64 * 32);
    gload16(gb, lB);
    ga += 32; gb += 32;
    __syncthreads();
    bf16x8 af[2], bfr[4];
#pragma unroll
    for (int i = 0; i < 2; ++i)
      af[i] = *reinterpret_cast<const bf16x8*>(As + (w * 32 + i * 16 + lr) * 32 + lkb);
#pragma unroll
    for (int j = 0; j < 4; ++j)
      bfr[j] = *reinterpret_cast<const bf16x8*>(Bs + (j * 16 + lr) * 32 + lkb);
#pragma unroll
    for (int i = 0; i < 2; ++i)
#pragma unroll
      for (int j = 0; j < 4; ++j)
        acc[i][j] = __builtin_amdgcn_mfma_f32_16x16x32_bf16(af[i], bfr[j], acc[i][j], 0, 0, 0);
  }

  int rbase = bm * 128 + w * 32;
  int cbase = bn * 64;
#pragma unroll
  for (int i = 0; i < 2; ++i) {
#pragma unroll
    for (int r = 0; r < 4; ++r) {
      int row = rbase + i * 16 + (l >> 4) * 4 + r;
#pragma unroll
      for (int j = 0; j < 4; ++j) {
        int col = cbase + j * 16 + lr;
        float v = acc[i][j][r] + bias[col];
        if (EPI == 0) {
          ((short*)Cout)[(size_t)row * N + col] = f2bf(v);
        } else if (EPI == 1) {
          v = 0.5f * v * (1.0f + erff(v * 0.70710678118654752f));
          ((short*)Cout)[(size_t)row * N + col] = f2bf(v);
        } else {
          ((float*)Cout)[(size_t)row * N + col] = v + resid[(size_t)row * N + col];
        }
      }
    }
  }
}

// ---------------- causal flash attention, QBLK=64, KVBLK=64 ------------------
// Swapped QK^T (S^T in regs) + in-register softmax + shfl-built P fragments.
// qkv: [ROWS][3*NE] bf16 (q|k|v). y: [ROWS][NE] bf16.
__global__ __launch_bounds__(256, 4) void attn_kernel(
    const short* __restrict__ qkv, short* __restrict__ y) {
  __shared__ short Ks[2][64 * 64];   // [kpos][hd], XOR-swizzled
  __shared__ short Vt[2][64 * 64];   // [hd][kpos], XOR-swizzled
  int t = threadIdx.x, w = t >> 6, l = t & 63;
  int lr = l & 15, g = l >> 4, lkb = g * 8;
  int qt = (gridDim.x - 1) - blockIdx.x;   // longest blocks first
  int bh = blockIdx.y;
  int b = bh / NH, h = bh % NH;
  int qbase = qt * 64;
  const int rstride = 3 * NE;

  // Q fragments: rows qbase + w*16 + lr  (B-operand: col=qrow, k=hd)
  const short* qrow = qkv + (size_t)(b * TT + qbase + w * 16 + lr) * rstride + h * HD + lkb;
  bf16x8 qf0 = *reinterpret_cast<const bf16x8*>(qrow);
  bf16x8 qf1 = *reinterpret_cast<const bf16x8*>(qrow + 32);

  f32x4 o[4];
#pragma unroll
  for (int j = 0; j < 4; ++j) o[j] = (f32x4){0.f, 0.f, 0.f, 0.f};
  float m_run = -3e38f, l_run = 0.f;   // per-lane: q-row (qbase + w*16 + lr)

  // staging geometry
  int hd2 = (t & 31) * 2;            // V: this thread owns hd pair
  int r0v = (t >> 5) * 8;            //    rows r0v..r0v+7
  int ci0 = t, ci1 = t + 256;        // K: 16B chunk ids
  int krow0 = ci0 >> 3, kc0 = ((ci0 & 7) ^ (krow0 & 7)) * 8;
  int krow1 = ci1 >> 3, kc1 = ((ci1 & 7) ^ (krow1 & 7)) * 8;
  int vba = (hd2 * 128 + r0v * 2) ^ ((hd2 & 7) << 4);
  int vbb = ((hd2 + 1) * 128 + r0v * 2) ^ (((hd2 + 1) & 7) << 4);

  const short* kvb = qkv + (size_t)(b * TT) * rstride + h * HD;

  unsigned int v32[8];
  // --- prologue: fully stage tile 0 into buffer 0 ---
  {
#pragma unroll
    for (int e = 0; e < 8; ++e)
      v32[e] = *reinterpret_cast<const unsigned int*>(
          kvb + (size_t)(r0v + e) * rstride + 2 * NE + hd2);
    gload16(kvb + (size_t)krow0 * rstride + NE + kc0, &Ks[0][ci0 * 8]);
    gload16(kvb + (size_t)krow1 * rstride + NE + kc1, &Ks[0][ci1 * 8]);
    bf16x8 ra, rb;
#pragma unroll
    for (int e = 0; e < 8; ++e) {
      ra[e] = (short)(v32[e] & 0xffffu);
      rb[e] = (short)(v32[e] >> 16);
    }
    *reinterpret_cast<bf16x8*>((char*)Vt[0] + vba) = ra;
    *reinterpret_cast<bf16x8*>((char*)Vt[0] + vbb) = rb;
  }

  int nkv = qt + 1;
  int qmin = qbase + w * 16;
  int srcA = ((g & 1) * 2) * 16 + lr;   // shfl src lanes for P-frag build
  int srcB = srcA + 16;
  bool ghi = (g >= 2);

  for (int kt = 0; kt < nkv; ++kt) {
    int bi = kt & 1;
    int kvbase = kt * 64;
    bool pre = (kt + 1 < nkv);
    __syncthreads();   // buf bi ready (gload drained, V writes visible)

    if (pre) {   // issue next tile's loads (latency hides under compute)
      const short* nb = kvb + (size_t)(kvbase + 64) * rstride;
#pragma unroll
      for (int e = 0; e < 8; ++e)
        v32[e] = *reinterpret_cast<const unsigned int*>(
            nb + (size_t)(r0v + e) * rstride + 2 * NE + hd2);
      gload16(nb + (size_t)krow0 * rstride + NE + kc0, &Ks[bi ^ 1][ci0 * 8]);
      gload16(nb + (size_t)krow1 * rstride + NE + kc1, &Ks[bi ^ 1][ci1 * 8]);
    }

    // --- QK^T (swapped): s[nt][reg] = S^T[kpos = kvbase+nt*16+g*4+reg][qrow=lr]
    f32x4 s[4];
#pragma unroll
    for (int nt = 0; nt < 4; ++nt) {
      int row = nt * 16 + lr;
      bf16x8 kf0 = *reinterpret_cast<const bf16x8*>(
          (char*)Ks[bi] + ((row * 128 + lkb * 2) ^ ((lr & 7) << 4)));
      bf16x8 kf1 = *reinterpret_cast<const bf16x8*>(
          (char*)Ks[bi] + ((row * 128 + 64 + lkb * 2) ^ ((lr & 7) << 4)));
      f32x4 st = (f32x4){0.f, 0.f, 0.f, 0.f};
      st = __builtin_amdgcn_mfma_f32_16x16x32_bf16(kf0, qf0, st, 0, 0, 0);
      st = __builtin_amdgcn_mfma_f32_16x16x32_bf16(kf1, qf1, st, 0, 0, 0);
      s[nt] = st;
    }

    // --- mask/scale ---
    if (kvbase + 63 > qmin) {   // diagonal tile
      int qabs = qmin + lr;
#pragma unroll
      for (int nt = 0; nt < 4; ++nt) {
#pragma unroll
        for (int r = 0; r < 4; ++r) {
          int kp = kvbase + nt * 16 + g * 4 + r;
          s[nt][r] = (kp <= qabs) ? s[nt][r] * 0.125f : -3e38f;
        }
      }
    } else {
#pragma unroll
      for (int nt = 0; nt < 4; ++nt)
#pragma unroll
        for (int r = 0; r < 4; ++r)
          s[nt][r] *= 0.125f;
    }

    // --- online softmax, fully in-register (row = lr, spread over 4 g-groups)
    float mx = s[0][0];
#pragma unroll
    for (int nt = 0; nt < 4; ++nt)
#pragma unroll
      for (int r = 0; r < 4; ++r) mx = fmaxf(mx, s[nt][r]);
    mx = fmaxf(mx, __shfl_xor(mx, 16));
    mx = fmaxf(mx, __shfl_xor(mx, 32));
    float mn = fmaxf(m_run, mx);
    float al = __expf(m_run - mn);
    m_run = mn;
    float rs = 0.f;
#pragma unroll
    for (int nt = 0; nt < 4; ++nt)
#pragma unroll
      for (int r = 0; r < 4; ++r) {
        float p = __expf(s[nt][r] - mn);
        s[nt][r] = p;
        rs += p;
      }
    rs += __shfl_xor(rs, 16);
    rs += __shfl_xor(rs, 32);
    l_run = l_run * al + rs;

    // alpha redistribution: o's rows are g*4+r; alpha lives at lane (row)
    float al0 = __shfl(al, g * 4 + 0);
    float al1 = __shfl(al, g * 4 + 1);
    float al2 = __shfl(al, g * 4 + 2);
    float al3 = __shfl(al, g * 4 + 3);
#pragma unroll
    for (int j = 0; j < 4; ++j) {
      o[j][0] *= al0; o[j][1] *= al1; o[j][2] *= al2; o[j][3] *= al3;
    }

    // --- pack P to bf16 pairs ---
    unsigned int pw[4][2];
#pragma unroll
    for (int nt = 0; nt < 4; ++nt)
#pragma unroll
      for (int pr = 0; pr < 2; ++pr)
        pw[nt][pr] = (unsigned int)(unsigned short)f2bf(s[nt][2 * pr]) |
                     ((unsigned int)(unsigned short)f2bf(s[nt][2 * pr + 1]) << 16);

    // --- PV: build P A-frag per 32-k chunk via shfl, then MFMA ---
#pragma unroll
    for (int c = 0; c < 2; ++c) {
      unsigned int a00 = __shfl(pw[c * 2 + 0][0], srcA);
      unsigned int a01 = __shfl(pw[c * 2 + 0][1], srcA);
      unsigned int a02 = __shfl(pw[c * 2 + 0][0], srcB);
      unsigned int a03 = __shfl(pw[c * 2 + 0][1], srcB);
      unsigned int a10 = __shfl(pw[c * 2 + 1][0], srcA);
      unsigned int a11 = __shfl(pw[c * 2 + 1][1], srcA);
      unsigned int a12 = __shfl(pw[c * 2 + 1][0], srcB);
      unsigned int a13 = __shfl(pw[c * 2 + 1][1], srcB);
      unsigned int u0 = ghi ? a10 : a00;
      unsigned int u1 = ghi ? a11 : a01;
      unsigned int u2 = ghi ? a12 : a02;
      unsigned int u3 = ghi ? a13 : a03;
      bf16x8 pa;
      pa[0] = (short)(u0 & 0xffffu); pa[1] = (short)(u0 >> 16);
      pa[2] = (short)(u1 & 0xffffu); pa[3] = (short)(u1 >> 16);
      pa[4] = (short)(u2 & 0xffffu); pa[5] = (short)(u2 >> 16);
      pa[6] = (short)(u3 & 0xffffu); pa[7] = (short)(u3 >> 16);
#pragma unroll
      for (int j = 0; j < 4; ++j) {
        int vrow = j * 16 + lr;
        bf16x8 vf = *reinterpret_cast<const bf16x8*>(
            (char*)Vt[bi] + ((vrow * 128 + c * 64 + lkb * 2) ^ ((lr & 7) << 4)));
        o[j] = __builtin_amdgcn_mfma_f32_16x16x32_bf16(pa, vf, o[j], 0, 0, 0);
      }
    }

    // --- finish next-tile V staging: extract + swizzled LDS write ---
    if (pre) {
      bf16x8 ra, rb;
#pragma unroll
      for (int e = 0; e < 8; ++e) {
        ra[e] = (short)(v32[e] & 0xffffu);
        rb[e] = (short)(v32[e] >> 16);
      }
      *reinterpret_cast<bf16x8*>((char*)Vt[bi ^ 1] + vba) = ra;
      *reinterpret_cast<bf16x8*>((char*)Vt[bi ^ 1] + vbb) = rb;
    }
  }

  // --- epilogue: normalize (inv lives at lane (row), o rows are g*4+r) ---
  float inv = 1.0f / l_run;
  float i0 = __shfl(inv, g * 4 + 0);
  float i1 = __shfl(inv, g * 4 + 1);
  float i2 = __shfl(inv, g * 4 + 2);
  float i3 = __shfl(inv, g * 4 + 3);
#pragma unroll
  for (int r = 0; r < 4; ++r) {
    float ir = (r == 0) ? i0 : (r == 1) ? i1 : (r == 2) ? i2 : i3;
    size_t row = (size_t)(b * TT + qbase + w * 16 + g * 4 + r);
#pragma unroll
    for (int j = 0; j < 4; ++j)
      y[row * NE + h * HD + j * 16 + lr] = f2bf(o[j][r] * ir);
  }
}

extern "C" void kernel_launch(void* const* d_in, const int* in_sizes, int n_in,
                              void* d_out, int out_size, void* d_ws, size_t ws_size,
                              hipStream_t stream) {
  (void)in_sizes; (void)n_in; (void)out_size; (void)ws_size;
  const float* x       = (const float*)d_in[0];
  const float* ln1_g   = (const float*)d_in[1];
  const float* ln1_b   = (const float*)d_in[2];
  const float* w_attn  = (const float*)d_in[3];
  const float* b_attn  = (const float*)d_in[4];
  const float* w_aproj = (const float*)d_in[5];
  const float* b_aproj = (const float*)d_in[6];
  const float* ln2_g   = (const float*)d_in[7];
  const float* ln2_b   = (const float*)d_in[8];
  const float* w_fc    = (const float*)d_in[9];
  const float* b_fc    = (const float*)d_in[10];
  const float* w_mproj = (const float*)d_in[11];
  const float* b_mproj = (const float*)d_in[12];

  char* ws = (char*)d_ws;
  size_t off = 0;
  auto alloc = [&](size_t bytes) {
    char* p = ws + off;
    off += (bytes + 255) & ~(size_t)255;
    return p;
  };
  short* wt_attn  = (short*)alloc((size_t)2304 * 768 * 2);
  short* wt_aproj = (short*)alloc((size_t)768 * 768 * 2);
  short* wt_fc    = (short*)alloc((size_t)3072 * 768 * 2);
  short* wt_mproj = (short*)alloc((size_t)768 * 3072 * 2);
  short* lnb  = (short*)alloc((size_t)ROWS * 768 * 2);
  short* qkvb = (short*)alloc((size_t)ROWS * 3072 * 2);
  short* yb   = (short*)alloc((size_t)ROWS * 768 * 2);
  float* x2   = (float*)alloc((size_t)ROWS * 768 * 4);

  wtrans_kernel<<<dim3(768 / 64, 2304 / 64), 256, 0, stream>>>(w_attn, wt_attn, 768, 2304);
  wtrans_kernel<<<dim3(768 / 64, 768 / 64), 256, 0, stream>>>(w_aproj, wt_aproj, 768, 768);
  wtrans_kernel<<<dim3(768 / 64, 3072 / 64), 256, 0, stream>>>(w_fc, wt_fc, 768, 3072);
  wtrans_kernel<<<dim3(3072 / 64, 768 / 64), 256, 0, stream>>>(w_mproj, wt_mproj, 3072, 768);

  ln_kernel<<<ROWS, 64, 0, stream>>>(x, ln1_g, ln1_b, lnb);
  gemm_kernel<0><<<dim3(2304 / 128, ROWS / 128), 256, 0, stream>>>(
      lnb, wt_attn, b_attn, nullptr, qkvb, ROWS, 2304, 768);
  attn_kernel<<<dim3(TT / 64, BB * NH), 256, 0, stream>>>(qkvb, yb);
  gemm64_kernel<2><<<dim3(768 / 64, ROWS / 128), 256, 0, stream>>>(
      yb, wt_aproj, b_aproj, x, x2, ROWS, 768, 768);
  ln_kernel<<<ROWS, 64, 0, stream>>>(x2, ln2_g, ln2_b, lnb);
  gemm_kernel<1><<<dim3(3072 / 128, ROWS / 128), 256, 0, stream>>>(
      lnb, wt_fc, b_fc, nullptr, qkvb, ROWS, 3072, 768);
  gemm64_kernel<2><<<dim3(768 / 64, ROWS / 128), 256, 0, stream>>>(
      qkvb, wt_mproj, b_mproj, x2, (float*)d_out, ROWS, 768, 3072);
}